// Round 1
// baseline (995.449 us; speedup 1.0000x reference)
//
#include <hip/hip_runtime.h>
#include <hip/hip_bf16.h>

#define N_NODES 50000
#define N_EDGES 640000
// FEAT = EMB = 128, HID = 512, B = 32

// ---------------- zero ----------------
__global__ void __launch_bounds__(256) zero_k(float4* __restrict__ p, int n4) {
    int i = blockIdx.x * 256 + threadIdx.x;
    if (i < n4) p[i] = make_float4(0.f, 0.f, 0.f, 0.f);
}

// ---------------- GEMM: C[M,128] = A[M,128] @ W[128,128] ----------------
// 64x64 output tile per block, 256 threads, 4x4 per thread, K in chunks of 32.
__global__ void __launch_bounds__(256) gemm128_k(const float* __restrict__ A,
                                                 const float* __restrict__ W,
                                                 float* __restrict__ C, int M) {
    __shared__ float As[32][64];  // k-major: As[k][m]
    __shared__ float Bs[32][64];  // Bs[k][n]
    int tid = threadIdx.x;
    int m0 = blockIdx.x * 64;
    int n0 = blockIdx.y * 64;
    int tr = (tid >> 4) << 2;   // 0..60
    int tc = (tid & 15) << 2;   // 0..60
    float acc[4][4] = {};
    for (int kk = 0; kk < 128; kk += 32) {
        #pragma unroll
        for (int i = 0; i < 2; i++) {
            int s = tid * 2 + i;            // 0..511
            // A tile: 64 rows x 8 float4
            int m  = s >> 3;
            int k4 = (s & 7) << 2;
            float4 v = make_float4(0.f, 0.f, 0.f, 0.f);
            int row = m0 + m;
            if (row < M) v = *(const float4*)(A + (size_t)row * 128 + kk + k4);
            As[k4 + 0][m] = v.x; As[k4 + 1][m] = v.y;
            As[k4 + 2][m] = v.z; As[k4 + 3][m] = v.w;
            // B tile: 32 k x 16 float4
            int kb = s >> 4;
            int n4 = (s & 15) << 2;
            *(float4*)&Bs[kb][n4] = *(const float4*)(W + (size_t)(kk + kb) * 128 + n0 + n4);
        }
        __syncthreads();
        #pragma unroll
        for (int k = 0; k < 32; k++) {
            float4 a = *(float4*)&As[k][tr];
            float4 b = *(float4*)&Bs[k][tc];
            acc[0][0] += a.x * b.x; acc[0][1] += a.x * b.y; acc[0][2] += a.x * b.z; acc[0][3] += a.x * b.w;
            acc[1][0] += a.y * b.x; acc[1][1] += a.y * b.y; acc[1][2] += a.y * b.z; acc[1][3] += a.y * b.w;
            acc[2][0] += a.z * b.x; acc[2][1] += a.z * b.y; acc[2][2] += a.z * b.z; acc[2][3] += a.z * b.w;
            acc[3][0] += a.w * b.x; acc[3][1] += a.w * b.y; acc[3][2] += a.w * b.z; acc[3][3] += a.w * b.w;
        }
        __syncthreads();
    }
    #pragma unroll
    for (int r = 0; r < 4; r++) {
        int row = m0 + tr + r;
        if (row < M)
            *(float4*)(C + (size_t)row * 128 + n0 + tc) =
                make_float4(acc[r][0], acc[r][1], acc[r][2], acc[r][3]);
    }
}

// ---------------- scatter-add (messages) + degree ----------------
// thread = (edge, feat); lanes of a wave share an edge -> coalesced gather + atomics.
__global__ void __launch_bounds__(256) scatter_k(const int* __restrict__ src,
                                                 const int* __restrict__ dst,
                                                 const float* __restrict__ t,
                                                 float* __restrict__ agg,
                                                 float* __restrict__ deg) {
    int idx = blockIdx.x * 256 + threadIdx.x;   // < E*128 = 81,920,000 < 2^31
    int e = idx >> 7;
    if (e >= N_EDGES) return;
    int f = idx & 127;
    int s = src[e];
    int d = dst[e];
    unsafeAtomicAdd(&agg[(size_t)d * 128 + f], t[(size_t)s * 128 + f]);
    if (f == 0) unsafeAtomicAdd(&deg[d], 1.0f);
}

// ---------------- combine: h = relu(agg/deg + root + b) ----------------
__global__ void __launch_bounds__(256) combine_k(const float4* __restrict__ agg,
                                                 const float* __restrict__ deg,
                                                 const float4* __restrict__ root,
                                                 const float* __restrict__ bias,
                                                 float4* __restrict__ hout) {
    int idx = blockIdx.x * 256 + threadIdx.x;  // over N*32 float4
    if (idx >= N_NODES * 32) return;
    int i  = idx >> 5;
    int c4 = (idx & 31) << 2;
    float inv = 1.f / fmaxf(deg[i], 1.f);
    float4 a = agg[idx];
    float4 r = root[idx];
    float4 o;
    o.x = fmaxf(a.x * inv + r.x + bias[c4 + 0], 0.f);
    o.y = fmaxf(a.y * inv + r.y + bias[c4 + 1], 0.f);
    o.z = fmaxf(a.z * inv + r.z + bias[c4 + 2], 0.f);
    o.w = fmaxf(a.w * inv + r.w + bias[c4 + 3], 0.f);
    hout[idx] = o;
}

// ---------------- message_embed: ME[32,128] = lh[32,512] @ Wp[512,128] + bp ----------------
__global__ void __launch_bounds__(256) me_k(const float* __restrict__ lh,
                                            const float* __restrict__ Wp,
                                            const float* __restrict__ bp,
                                            float* __restrict__ me) {
    int o = blockIdx.x * 256 + threadIdx.x;  // 4096 outputs
    if (o >= 32 * 128) return;
    int i = o >> 7, c = o & 127;
    float acc = bp[c];
    for (int k = 0; k < 512; k++)
        acc += lh[i * 512 + k] * Wp[k * 128 + c];
    me[o] = acc;
}

// ---------------- scores: S[N,32] = h[N,128] @ ME^T ----------------
__global__ void __launch_bounds__(256) scores_k(const float* __restrict__ h,
                                                const float* __restrict__ me,
                                                float* __restrict__ S) {
    __shared__ float meT[128 * 32];  // meT[k*32+b], 16 KB
    int tid = threadIdx.x;
    for (int s = tid; s < 4096; s += 256) {
        int b = s >> 7, k = s & 127;
        meT[k * 32 + b] = me[s];
    }
    __syncthreads();
    int b  = tid & 31;
    int i  = blockIdx.x * 8 + (tid >> 5);
    if (i >= N_NODES) return;
    const float* hr = h + (size_t)i * 128;
    float acc = 0.f;
    #pragma unroll 8
    for (int k = 0; k < 128; k++) acc += hr[k] * meT[k * 32 + b];
    S[(size_t)i * 32 + b] = acc;
}

// ---------------- column-wise (axis=0) online softmax stats ----------------
__global__ void __launch_bounds__(256) colstats_k(const float* __restrict__ S,
                                                  float* __restrict__ colm,
                                                  float* __restrict__ cols) {
    int b = blockIdx.x;   // 0..31
    int t = threadIdx.x;
    float m = -3.4e38f, s = 0.f;
    for (int i = t; i < N_NODES; i += 256) {
        float v = S[(size_t)i * 32 + b];
        if (v > m) { s = s * __expf(m - v) + 1.f; m = v; }
        else       { s += __expf(v - m); }
    }
    __shared__ float sm[256], ss[256];
    sm[t] = m; ss[t] = s;
    __syncthreads();
    for (int off = 128; off > 0; off >>= 1) {
        if (t < off) {
            float m2 = sm[t + off], s2 = ss[t + off];
            float M = fmaxf(sm[t], m2);
            ss[t] = ss[t] * __expf(sm[t] - M) + s2 * __expf(m2 - M);
            sm[t] = M;
        }
        __syncthreads();
    }
    if (t == 0) { colm[b] = sm[0]; cols[b] = logf(ss[0]); }
}

__global__ void __launch_bounds__(256) final_k(const float* __restrict__ S,
                                               const float* __restrict__ colm,
                                               const float* __restrict__ cols,
                                               float* __restrict__ out) {
    int idx = blockIdx.x * 256 + threadIdx.x;  // N*32
    if (idx >= N_NODES * 32) return;
    int b = idx & 31;
    out[idx] = S[idx] - colm[b] - cols[b];
}

extern "C" void kernel_launch(void* const* d_in, const int* in_sizes, int n_in,
                              void* d_out, int out_size, void* d_ws, size_t ws_size,
                              hipStream_t stream) {
    const float* x       = (const float*)d_in[0];
    const int*   ei      = (const int*)d_in[1];   // [2, E] int
    const float* lh      = (const float*)d_in[2];
    const float* W1_rel  = (const float*)d_in[3];
    const float* W1_root = (const float*)d_in[4];
    const float* b1      = (const float*)d_in[5];
    const float* W2_rel  = (const float*)d_in[6];
    const float* W2_root = (const float*)d_in[7];
    const float* b2      = (const float*)d_in[8];
    const float* Wp      = (const float*)d_in[9];
    const float* bp      = (const float*)d_in[10];
    float* out = (float*)d_out;
    float* ws  = (float*)d_ws;

    // workspace layout (floats)
    float* A    = ws;                   // 6,400,000  (t1 / h1 / h2)
    float* Bb   = ws + 6400000;         // 6,400,000  (agg)
    float* deg  = ws + 12800000;        // 65,536 slot (50,000 used)
    float* Cc   = ws + 12865536;        // 6,400,000  (root / t2)
    float* ME   = ws + 19265536;        // 4,096
    float* S    = ws + 19269632;        // 1,600,000
    float* colm = ws + 20869632;        // 32
    float* cols = ws + 20869664;        // 32

    const int* srcp = ei;
    const int* dstp = ei + N_EDGES;

    dim3 g_gemm(782, 2);
    const int zero_n4   = (6400000 + 65536) / 4;        // agg + deg region
    const int zero_grid = (zero_n4 + 255) / 256;
    const int scat_grid = (N_EDGES * 128) / 256;        // 320,000
    const int ew_grid   = (N_NODES * 32 + 255) / 256;   // 6,250

    // message embed (independent)
    me_k<<<16, 256, 0, stream>>>(lh, Wp, bp, ME);

    // ---- layer 1 ----
    gemm128_k<<<g_gemm, 256, 0, stream>>>(x, W1_rel, A, N_NODES);        // t1 = x@W1_rel
    zero_k<<<zero_grid, 256, 0, stream>>>((float4*)Bb, zero_n4);         // agg=0, deg=0
    scatter_k<<<scat_grid, 256, 0, stream>>>(srcp, dstp, A, Bb, deg);
    gemm128_k<<<g_gemm, 256, 0, stream>>>(x, W1_root, Cc, N_NODES);      // root1
    combine_k<<<ew_grid, 256, 0, stream>>>((const float4*)Bb, deg,
                                           (const float4*)Cc, b1, (float4*)A);  // h1 -> A

    // ---- layer 2 ----
    gemm128_k<<<g_gemm, 256, 0, stream>>>(A, W2_rel, Cc, N_NODES);       // t2
    zero_k<<<zero_grid, 256, 0, stream>>>((float4*)Bb, zero_n4);
    scatter_k<<<scat_grid, 256, 0, stream>>>(srcp, dstp, Cc, Bb, deg);
    gemm128_k<<<g_gemm, 256, 0, stream>>>(A, W2_root, Cc, N_NODES);      // root2
    combine_k<<<ew_grid, 256, 0, stream>>>((const float4*)Bb, deg,
                                           (const float4*)Cc, b2, (float4*)A);  // h2 -> A

    // ---- scores + column log-softmax ----
    scores_k<<<N_NODES / 8, 256, 0, stream>>>(A, ME, S);
    colstats_k<<<32, 256, 0, stream>>>(S, colm, cols);
    final_k<<<ew_grid, 256, 0, stream>>>(S, colm, cols, out);
}

// Round 2
// 524.329 us; speedup vs baseline: 1.8985x; 1.8985x over previous
//
#include <hip/hip_runtime.h>
#include <hip/hip_bf16.h>

#define N_NODES 50000
#define N_EDGES 640000
// FEAT = EMB = 128, HID = 512, B = 32

// ---------------- zero int counters ----------------
__global__ void __launch_bounds__(256) zero_cnt_k(int* __restrict__ p, int n) {
    int i = blockIdx.x * 256 + threadIdx.x;
    if (i < n) p[i] = 0;
}

// ---------------- degree histogram ----------------
__global__ void __launch_bounds__(256) hist_k(const int* __restrict__ dst,
                                              int* __restrict__ cnt) {
    int e = blockIdx.x * 256 + threadIdx.x;
    if (e < N_EDGES) atomicAdd(&cnt[dst[e]], 1);
}

// ---------------- scan stage 1: per-1024-chunk exclusive scan ----------------
__global__ void __launch_bounds__(256) scan1_k(const int* __restrict__ cnt,
                                               int* __restrict__ row,
                                               int* __restrict__ bsum) {
    __shared__ int sm[256];
    int t = threadIdx.x;
    int base = blockIdx.x * 1024 + t * 4;
    int c0 = (base + 0 < N_NODES) ? cnt[base + 0] : 0;
    int c1 = (base + 1 < N_NODES) ? cnt[base + 1] : 0;
    int c2 = (base + 2 < N_NODES) ? cnt[base + 2] : 0;
    int c3 = (base + 3 < N_NODES) ? cnt[base + 3] : 0;
    int s4 = c0 + c1 + c2 + c3;
    sm[t] = s4;
    __syncthreads();
    for (int off = 1; off < 256; off <<= 1) {
        int v = (t >= off) ? sm[t - off] : 0;
        __syncthreads();
        sm[t] += v;
        __syncthreads();
    }
    int excl = sm[t] - s4;
    if (base + 0 < N_NODES) row[base + 0] = excl;
    if (base + 1 < N_NODES) row[base + 1] = excl + c0;
    if (base + 2 < N_NODES) row[base + 2] = excl + c0 + c1;
    if (base + 3 < N_NODES) row[base + 3] = excl + c0 + c1 + c2;
    if (t == 255) bsum[blockIdx.x] = sm[255];
}

// ---------------- scan stage 2: scan the 49 block sums ----------------
__global__ void __launch_bounds__(64) scan2_k(int* __restrict__ bsum, int nb) {
    if (threadIdx.x == 0 && blockIdx.x == 0) {
        int running = 0;
        for (int k = 0; k < nb; k++) { int v = bsum[k]; bsum[k] = running; running += v; }
    }
}

// ---------------- scan stage 3: add offsets, init cursor, cap row_ptr ----------------
__global__ void __launch_bounds__(256) scan3_k(int* __restrict__ row,
                                               const int* __restrict__ bsum,
                                               int* __restrict__ cur) {
    int i = blockIdx.x * 256 + threadIdx.x;
    if (i < N_NODES) {
        int v = row[i] + bsum[i >> 10];
        row[i] = v;
        cur[i] = v;
        if (i == 0) row[N_NODES] = N_EDGES;
    }
}

// ---------------- placement: sorted_src grouped by dst ----------------
__global__ void __launch_bounds__(256) place_k(const int* __restrict__ src,
                                               const int* __restrict__ dst,
                                               int* __restrict__ cur,
                                               int* __restrict__ ssrc) {
    int e = blockIdx.x * 256 + threadIdx.x;
    if (e < N_EDGES) {
        int p = atomicAdd(&cur[dst[e]], 1);
        ssrc[p] = src[e];
    }
}

// ---------------- GEMM: C[M,128] = A[M,128] @ W[128,128] ----------------
__global__ void __launch_bounds__(256) gemm128_k(const float* __restrict__ A,
                                                 const float* __restrict__ W,
                                                 float* __restrict__ C, int M) {
    __shared__ float As[32][64];  // k-major: As[k][m]
    __shared__ float Bs[32][64];  // Bs[k][n]
    int tid = threadIdx.x;
    int m0 = blockIdx.x * 64;
    int n0 = blockIdx.y * 64;
    int tr = (tid >> 4) << 2;
    int tc = (tid & 15) << 2;
    float acc[4][4] = {};
    for (int kk = 0; kk < 128; kk += 32) {
        #pragma unroll
        for (int i = 0; i < 2; i++) {
            int s = tid * 2 + i;
            int m  = s >> 3;
            int k4 = (s & 7) << 2;
            float4 v = make_float4(0.f, 0.f, 0.f, 0.f);
            int rowi = m0 + m;
            if (rowi < M) v = *(const float4*)(A + (size_t)rowi * 128 + kk + k4);
            As[k4 + 0][m] = v.x; As[k4 + 1][m] = v.y;
            As[k4 + 2][m] = v.z; As[k4 + 3][m] = v.w;
            int kb = s >> 4;
            int n4 = (s & 15) << 2;
            *(float4*)&Bs[kb][n4] = *(const float4*)(W + (size_t)(kk + kb) * 128 + n0 + n4);
        }
        __syncthreads();
        #pragma unroll
        for (int k = 0; k < 32; k++) {
            float4 a = *(float4*)&As[k][tr];
            float4 b = *(float4*)&Bs[k][tc];
            acc[0][0] += a.x * b.x; acc[0][1] += a.x * b.y; acc[0][2] += a.x * b.z; acc[0][3] += a.x * b.w;
            acc[1][0] += a.y * b.x; acc[1][1] += a.y * b.y; acc[1][2] += a.y * b.z; acc[1][3] += a.y * b.w;
            acc[2][0] += a.z * b.x; acc[2][1] += a.z * b.y; acc[2][2] += a.z * b.z; acc[2][3] += a.z * b.w;
            acc[3][0] += a.w * b.x; acc[3][1] += a.w * b.y; acc[3][2] += a.w * b.z; acc[3][3] += a.w * b.w;
        }
        __syncthreads();
    }
    #pragma unroll
    for (int r = 0; r < 4; r++) {
        int rowi = m0 + tr + r;
        if (rowi < M)
            *(float4*)(C + (size_t)rowi * 128 + n0 + tc) =
                make_float4(acc[r][0], acc[r][1], acc[r][2], acc[r][3]);
    }
}

// ---------------- fused gather-aggregate + mean + root + bias + relu ----------------
// one 128-thread block per destination node; thread = feature
__global__ void __launch_bounds__(128) agg_k(const int* __restrict__ row,
                                             const int* __restrict__ ssrc,
                                             const float* __restrict__ t,
                                             const float* __restrict__ root,
                                             const float* __restrict__ bias,
                                             float* __restrict__ hout) {
    int i = blockIdx.x;
    int f = threadIdx.x;
    int beg = row[i], end = row[i + 1];
    float acc = 0.f;
    for (int e = beg; e < end; e++) {
        int s = ssrc[e];
        acc += t[(size_t)s * 128 + f];
    }
    float deg = (float)(end - beg);
    float inv = 1.f / fmaxf(deg, 1.f);
    float v = acc * inv + root[(size_t)i * 128 + f] + bias[f];
    hout[(size_t)i * 128 + f] = fmaxf(v, 0.f);
}

// ---------------- message_embed: ME[32,128] = lh[32,512] @ Wp[512,128] + bp ----------------
__global__ void __launch_bounds__(256) me_k(const float* __restrict__ lh,
                                            const float* __restrict__ Wp,
                                            const float* __restrict__ bp,
                                            float* __restrict__ me) {
    int o = blockIdx.x * 256 + threadIdx.x;
    if (o >= 32 * 128) return;
    int i = o >> 7, c = o & 127;
    float acc = bp[c];
    for (int k = 0; k < 512; k++)
        acc += lh[i * 512 + k] * Wp[k * 128 + c];
    me[o] = acc;
}

// ---------------- scores: S[N,32] = h[N,128] @ ME^T ----------------
__global__ void __launch_bounds__(256) scores_k(const float* __restrict__ h,
                                                const float* __restrict__ me,
                                                float* __restrict__ S) {
    __shared__ float meT[128 * 32];
    int tid = threadIdx.x;
    for (int s = tid; s < 4096; s += 256) {
        int b = s >> 7, k = s & 127;
        meT[k * 32 + b] = me[s];
    }
    __syncthreads();
    int b  = tid & 31;
    int i  = blockIdx.x * 8 + (tid >> 5);
    if (i >= N_NODES) return;
    const float* hr = h + (size_t)i * 128;
    float acc = 0.f;
    #pragma unroll 8
    for (int k = 0; k < 128; k++) acc += hr[k] * meT[k * 32 + b];
    S[(size_t)i * 32 + b] = acc;
}

// ---------------- column softmax stats, stage 1: 32 cols x 8 chunks ----------------
__global__ void __launch_bounds__(256) cs1_k(const float* __restrict__ S,
                                             float* __restrict__ pm,
                                             float* __restrict__ ps) {
    int b = blockIdx.x;   // column
    int c = blockIdx.y;   // chunk
    int t = threadIdx.x;
    int lo = c * 6250;
    int hi = min(lo + 6250, N_NODES);
    float m = -3.4e38f, s = 0.f;
    for (int i = lo + t; i < hi; i += 256) {
        float v = S[(size_t)i * 32 + b];
        if (v > m) { s = s * __expf(m - v) + 1.f; m = v; }
        else       { s += __expf(v - m); }
    }
    __shared__ float sm[256], ss[256];
    sm[t] = m; ss[t] = s;
    __syncthreads();
    for (int off = 128; off > 0; off >>= 1) {
        if (t < off) {
            float m2 = sm[t + off], s2 = ss[t + off];
            float M = fmaxf(sm[t], m2);
            ss[t] = ss[t] * __expf(sm[t] - M) + s2 * __expf(m2 - M);
            sm[t] = M;
        }
        __syncthreads();
    }
    if (t == 0) { pm[b * 8 + c] = sm[0]; ps[b * 8 + c] = ss[0]; }
}

// ---------------- column softmax stats, stage 2 ----------------
__global__ void __launch_bounds__(64) cs2_k(const float* __restrict__ pm,
                                            const float* __restrict__ ps,
                                            float* __restrict__ colm,
                                            float* __restrict__ cols) {
    int b = threadIdx.x;
    if (b >= 32) return;
    float m = -3.4e38f, s = 0.f;
    for (int c = 0; c < 8; c++) {
        float m2 = pm[b * 8 + c], s2 = ps[b * 8 + c];
        float M = fmaxf(m, m2);
        s = s * __expf(m - M) + s2 * __expf(m2 - M);
        m = M;
    }
    colm[b] = m;
    cols[b] = logf(s);
}

__global__ void __launch_bounds__(256) final_k(const float* __restrict__ S,
                                               const float* __restrict__ colm,
                                               const float* __restrict__ cols,
                                               float* __restrict__ out) {
    int idx = blockIdx.x * 256 + threadIdx.x;
    if (idx >= N_NODES * 32) return;
    int b = idx & 31;
    out[idx] = S[idx] - colm[b] - cols[b];
}

extern "C" void kernel_launch(void* const* d_in, const int* in_sizes, int n_in,
                              void* d_out, int out_size, void* d_ws, size_t ws_size,
                              hipStream_t stream) {
    const float* x       = (const float*)d_in[0];
    const int*   ei      = (const int*)d_in[1];
    const float* lh      = (const float*)d_in[2];
    const float* W1_rel  = (const float*)d_in[3];
    const float* W1_root = (const float*)d_in[4];
    const float* b1      = (const float*)d_in[5];
    const float* W2_rel  = (const float*)d_in[6];
    const float* W2_root = (const float*)d_in[7];
    const float* b2      = (const float*)d_in[8];
    const float* Wp      = (const float*)d_in[9];
    const float* bp      = (const float*)d_in[10];
    float* out = (float*)d_out;
    float* ws  = (float*)d_ws;

    // workspace layout (float elements)
    float* buf0 = ws;                       // 6,400,000  (t)
    float* buf1 = ws + 6400000;             // 6,400,000  (root)
    float* buf2 = ws + 12800000;            // 6,400,000  (h)
    int*   cnt  = (int*)(ws + 19200000);    // 50,000
    int*   row  = (int*)(ws + 19250048);    // 50,001
    int*   cur  = (int*)(ws + 19300096);    // 50,000
    int*   bsum = (int*)(ws + 19350144);    // 64
    float* ME   = ws + 19350272;            // 4,096
    float* colm = ws + 19354368;            // 32
    float* cols = ws + 19354400;            // 32
    float* pm   = ws + 19354432;            // 256
    float* ps   = ws + 19354688;            // 256
    int*   ssrc = (int*)(ws + 19355008);    // 640,000 (dead after agg2)
    float* S    = ws + 19355008;            // 1,600,000 (overlaps ssrc: written after)

    const int* srcp = ei;
    const int* dstp = ei + N_EDGES;

    dim3 g_gemm(782, 2);
    const int e_grid  = (N_EDGES + 255) / 256;          // 2,500
    const int n_grid  = (N_NODES + 255) / 256;          // 196
    const int ew_grid = (N_NODES * 32 + 255) / 256;     // 6,250

    // independent: message embed
    me_k<<<16, 256, 0, stream>>>(lh, Wp, bp, ME);

    // ---- CSR build (once, reused by both layers) ----
    zero_cnt_k<<<n_grid, 256, 0, stream>>>(cnt, N_NODES);
    hist_k<<<e_grid, 256, 0, stream>>>(dstp, cnt);
    scan1_k<<<49, 256, 0, stream>>>(cnt, row, bsum);
    scan2_k<<<1, 64, 0, stream>>>(bsum, 49);
    scan3_k<<<n_grid, 256, 0, stream>>>(row, bsum, cur);
    place_k<<<e_grid, 256, 0, stream>>>(srcp, dstp, cur, ssrc);

    // ---- layer 1 ----
    gemm128_k<<<g_gemm, 256, 0, stream>>>(x, W1_rel, buf0, N_NODES);   // t1
    gemm128_k<<<g_gemm, 256, 0, stream>>>(x, W1_root, buf1, N_NODES);  // root1
    agg_k<<<N_NODES, 128, 0, stream>>>(row, ssrc, buf0, buf1, b1, buf2); // h1

    // ---- layer 2 ----
    gemm128_k<<<g_gemm, 256, 0, stream>>>(buf2, W2_rel, buf0, N_NODES);  // t2
    gemm128_k<<<g_gemm, 256, 0, stream>>>(buf2, W2_root, buf1, N_NODES); // root2
    agg_k<<<N_NODES, 128, 0, stream>>>(row, ssrc, buf0, buf1, b2, buf2); // h2

    // ---- scores + column log-softmax ----
    scores_k<<<N_NODES / 8, 256, 0, stream>>>(buf2, ME, S);
    cs1_k<<<dim3(32, 8), 256, 0, stream>>>(S, pm, ps);
    cs2_k<<<1, 64, 0, stream>>>(pm, ps, colm, cols);
    final_k<<<ew_grid, 256, 0, stream>>>(S, colm, cols, out);
}

// Round 3
// 456.184 us; speedup vs baseline: 2.1821x; 1.1494x over previous
//
#include <hip/hip_runtime.h>
#include <hip/hip_bf16.h>

#define N_NODES 50000
#define N_EDGES 640000
// FEAT = EMB = 128, HID = 512, B = 32

__device__ __forceinline__ float bf2f(unsigned short u) {
    return __uint_as_float(((unsigned int)u) << 16);
}
__device__ __forceinline__ unsigned short f2bf(float x) {
    unsigned int u = __float_as_uint(x);
    u = (u + 0x7fffu + ((u >> 16) & 1u)) >> 16;   // RNE
    return (unsigned short)u;
}

// ---------------- zero int counters ----------------
__global__ void __launch_bounds__(256) zero_cnt_k(int* __restrict__ p, int n) {
    int i = blockIdx.x * 256 + threadIdx.x;
    if (i < n) p[i] = 0;
}

// ---------------- degree histogram ----------------
__global__ void __launch_bounds__(256) hist_k(const int* __restrict__ dst,
                                              int* __restrict__ cnt) {
    int e = blockIdx.x * 256 + threadIdx.x;
    if (e < N_EDGES) atomicAdd(&cnt[dst[e]], 1);
}

// ---------------- scan stage 1 ----------------
__global__ void __launch_bounds__(256) scan1_k(const int* __restrict__ cnt,
                                               int* __restrict__ row,
                                               int* __restrict__ bsum) {
    __shared__ int sm[256];
    int t = threadIdx.x;
    int base = blockIdx.x * 1024 + t * 4;
    int c0 = (base + 0 < N_NODES) ? cnt[base + 0] : 0;
    int c1 = (base + 1 < N_NODES) ? cnt[base + 1] : 0;
    int c2 = (base + 2 < N_NODES) ? cnt[base + 2] : 0;
    int c3 = (base + 3 < N_NODES) ? cnt[base + 3] : 0;
    int s4 = c0 + c1 + c2 + c3;
    sm[t] = s4;
    __syncthreads();
    for (int off = 1; off < 256; off <<= 1) {
        int v = (t >= off) ? sm[t - off] : 0;
        __syncthreads();
        sm[t] += v;
        __syncthreads();
    }
    int excl = sm[t] - s4;
    if (base + 0 < N_NODES) row[base + 0] = excl;
    if (base + 1 < N_NODES) row[base + 1] = excl + c0;
    if (base + 2 < N_NODES) row[base + 2] = excl + c0 + c1;
    if (base + 3 < N_NODES) row[base + 3] = excl + c0 + c1 + c2;
    if (t == 255) bsum[blockIdx.x] = sm[255];
}

// ---------------- scan stage 2 ----------------
__global__ void __launch_bounds__(64) scan2_k(int* __restrict__ bsum, int nb) {
    if (threadIdx.x == 0 && blockIdx.x == 0) {
        int running = 0;
        for (int k = 0; k < nb; k++) { int v = bsum[k]; bsum[k] = running; running += v; }
    }
}

// ---------------- scan stage 3 ----------------
__global__ void __launch_bounds__(256) scan3_k(int* __restrict__ row,
                                               const int* __restrict__ bsum,
                                               int* __restrict__ cur) {
    int i = blockIdx.x * 256 + threadIdx.x;
    if (i < N_NODES) {
        int v = row[i] + bsum[i >> 10];
        row[i] = v;
        cur[i] = v;
        if (i == 0) row[N_NODES] = N_EDGES;
    }
}

// ---------------- placement ----------------
__global__ void __launch_bounds__(256) place_k(const int* __restrict__ src,
                                               const int* __restrict__ dst,
                                               int* __restrict__ cur,
                                               int* __restrict__ ssrc) {
    int e = blockIdx.x * 256 + threadIdx.x;
    if (e < N_EDGES) {
        int p = atomicAdd(&cur[dst[e]], 1);
        ssrc[p] = src[e];
    }
}

// ---------------- GEMM fp32 out: C[M,128] = A[M,128] @ W[128,128] ----------------
__global__ void __launch_bounds__(256) gemm128_k(const float* __restrict__ A,
                                                 const float* __restrict__ W,
                                                 float* __restrict__ C, int M) {
    __shared__ float As[32][64];
    __shared__ float Bs[32][64];
    int tid = threadIdx.x;
    int m0 = blockIdx.x * 64;
    int n0 = blockIdx.y * 64;
    int tr = (tid >> 4) << 2;
    int tc = (tid & 15) << 2;
    float acc[4][4] = {};
    for (int kk = 0; kk < 128; kk += 32) {
        #pragma unroll
        for (int i = 0; i < 2; i++) {
            int s = tid * 2 + i;
            int m  = s >> 3;
            int k4 = (s & 7) << 2;
            float4 v = make_float4(0.f, 0.f, 0.f, 0.f);
            int rowi = m0 + m;
            if (rowi < M) v = *(const float4*)(A + (size_t)rowi * 128 + kk + k4);
            As[k4 + 0][m] = v.x; As[k4 + 1][m] = v.y;
            As[k4 + 2][m] = v.z; As[k4 + 3][m] = v.w;
            int kb = s >> 4;
            int n4 = (s & 15) << 2;
            *(float4*)&Bs[kb][n4] = *(const float4*)(W + (size_t)(kk + kb) * 128 + n0 + n4);
        }
        __syncthreads();
        #pragma unroll
        for (int k = 0; k < 32; k++) {
            float4 a = *(float4*)&As[k][tr];
            float4 b = *(float4*)&Bs[k][tc];
            acc[0][0] += a.x * b.x; acc[0][1] += a.x * b.y; acc[0][2] += a.x * b.z; acc[0][3] += a.x * b.w;
            acc[1][0] += a.y * b.x; acc[1][1] += a.y * b.y; acc[1][2] += a.y * b.z; acc[1][3] += a.y * b.w;
            acc[2][0] += a.z * b.x; acc[2][1] += a.z * b.y; acc[2][2] += a.z * b.z; acc[2][3] += a.z * b.w;
            acc[3][0] += a.w * b.x; acc[3][1] += a.w * b.y; acc[3][2] += a.w * b.z; acc[3][3] += a.w * b.w;
        }
        __syncthreads();
    }
    #pragma unroll
    for (int r = 0; r < 4; r++) {
        int rowi = m0 + tr + r;
        if (rowi < M)
            *(float4*)(C + (size_t)rowi * 128 + n0 + tc) =
                make_float4(acc[r][0], acc[r][1], acc[r][2], acc[r][3]);
    }
}

// ---------------- GEMM bf16 out (for the gather table) ----------------
__global__ void __launch_bounds__(256) gemm128_bf16_k(const float* __restrict__ A,
                                                      const float* __restrict__ W,
                                                      unsigned short* __restrict__ C, int M) {
    __shared__ float As[32][64];
    __shared__ float Bs[32][64];
    int tid = threadIdx.x;
    int m0 = blockIdx.x * 64;
    int n0 = blockIdx.y * 64;
    int tr = (tid >> 4) << 2;
    int tc = (tid & 15) << 2;
    float acc[4][4] = {};
    for (int kk = 0; kk < 128; kk += 32) {
        #pragma unroll
        for (int i = 0; i < 2; i++) {
            int s = tid * 2 + i;
            int m  = s >> 3;
            int k4 = (s & 7) << 2;
            float4 v = make_float4(0.f, 0.f, 0.f, 0.f);
            int rowi = m0 + m;
            if (rowi < M) v = *(const float4*)(A + (size_t)rowi * 128 + kk + k4);
            As[k4 + 0][m] = v.x; As[k4 + 1][m] = v.y;
            As[k4 + 2][m] = v.z; As[k4 + 3][m] = v.w;
            int kb = s >> 4;
            int n4 = (s & 15) << 2;
            *(float4*)&Bs[kb][n4] = *(const float4*)(W + (size_t)(kk + kb) * 128 + n0 + n4);
        }
        __syncthreads();
        #pragma unroll
        for (int k = 0; k < 32; k++) {
            float4 a = *(float4*)&As[k][tr];
            float4 b = *(float4*)&Bs[k][tc];
            acc[0][0] += a.x * b.x; acc[0][1] += a.x * b.y; acc[0][2] += a.x * b.z; acc[0][3] += a.x * b.w;
            acc[1][0] += a.y * b.x; acc[1][1] += a.y * b.y; acc[1][2] += a.y * b.z; acc[1][3] += a.y * b.w;
            acc[2][0] += a.z * b.x; acc[2][1] += a.z * b.y; acc[2][2] += a.z * b.z; acc[2][3] += a.z * b.w;
            acc[3][0] += a.w * b.x; acc[3][1] += a.w * b.y; acc[3][2] += a.w * b.z; acc[3][3] += a.w * b.w;
        }
        __syncthreads();
    }
    #pragma unroll
    for (int r = 0; r < 4; r++) {
        int rowi = m0 + tr + r;
        if (rowi < M) {
            ushort4 o;
            o.x = f2bf(acc[r][0]); o.y = f2bf(acc[r][1]);
            o.z = f2bf(acc[r][2]); o.w = f2bf(acc[r][3]);
            *(ushort4*)(C + (size_t)rowi * 128 + n0 + tc) = o;
        }
    }
}

// ---------------- fused gather-aggregate (bf16 table) + mean + root + bias + relu ----------------
// one wave per node, lane = feature pair
__global__ void __launch_bounds__(256) agg_k(const int* __restrict__ row,
                                             const int* __restrict__ ssrc,
                                             const unsigned short* __restrict__ t,
                                             const float* __restrict__ root,
                                             const float* __restrict__ bias,
                                             float* __restrict__ hout) {
    int node = blockIdx.x * 4 + (threadIdx.x >> 6);
    if (node >= N_NODES) return;
    int lane = threadIdx.x & 63;
    int beg = row[node], end = row[node + 1];
    float a0 = 0.f, a1 = 0.f;
    int e = beg;
    for (; e + 1 < end; e += 2) {
        int s0 = ssrc[e], s1 = ssrc[e + 1];
        ushort2 u0 = *(const ushort2*)(t + (size_t)s0 * 128 + lane * 2);
        ushort2 u1 = *(const ushort2*)(t + (size_t)s1 * 128 + lane * 2);
        a0 += bf2f(u0.x) + bf2f(u1.x);
        a1 += bf2f(u0.y) + bf2f(u1.y);
    }
    if (e < end) {
        int s0 = ssrc[e];
        ushort2 u0 = *(const ushort2*)(t + (size_t)s0 * 128 + lane * 2);
        a0 += bf2f(u0.x);
        a1 += bf2f(u0.y);
    }
    float inv = 1.f / fmaxf((float)(end - beg), 1.f);
    int f = lane * 2;
    float2 r = *(const float2*)(root + (size_t)node * 128 + f);
    float v0 = fmaxf(a0 * inv + r.x + bias[f + 0], 0.f);
    float v1 = fmaxf(a1 * inv + r.y + bias[f + 1], 0.f);
    *(float2*)(hout + (size_t)node * 128 + f) = make_float2(v0, v1);
}

// ---------------- message_embed ----------------
__global__ void __launch_bounds__(256) me_k(const float* __restrict__ lh,
                                            const float* __restrict__ Wp,
                                            const float* __restrict__ bp,
                                            float* __restrict__ me) {
    int o = blockIdx.x * 256 + threadIdx.x;
    if (o >= 32 * 128) return;
    int i = o >> 7, c = o & 127;
    float acc = bp[c];
    for (int k = 0; k < 512; k++)
        acc += lh[i * 512 + k] * Wp[k * 128 + c];
    me[o] = acc;
}

// ---------------- scores ----------------
__global__ void __launch_bounds__(256) scores_k(const float* __restrict__ h,
                                                const float* __restrict__ me,
                                                float* __restrict__ S) {
    __shared__ float meT[128 * 32];
    int tid = threadIdx.x;
    for (int s = tid; s < 4096; s += 256) {
        int b = s >> 7, k = s & 127;
        meT[k * 32 + b] = me[s];
    }
    __syncthreads();
    int b  = tid & 31;
    int i  = blockIdx.x * 8 + (tid >> 5);
    if (i >= N_NODES) return;
    const float* hr = h + (size_t)i * 128;
    float acc = 0.f;
    #pragma unroll 8
    for (int k = 0; k < 128; k++) acc += hr[k] * meT[k * 32 + b];
    S[(size_t)i * 32 + b] = acc;
}

// ---------------- column softmax stats, stage 1 ----------------
__global__ void __launch_bounds__(256) cs1_k(const float* __restrict__ S,
                                             float* __restrict__ pm,
                                             float* __restrict__ ps) {
    int b = blockIdx.x;
    int c = blockIdx.y;
    int t = threadIdx.x;
    int lo = c * 6250;
    int hi = min(lo + 6250, N_NODES);
    float m = -3.4e38f, s = 0.f;
    for (int i = lo + t; i < hi; i += 256) {
        float v = S[(size_t)i * 32 + b];
        if (v > m) { s = s * __expf(m - v) + 1.f; m = v; }
        else       { s += __expf(v - m); }
    }
    __shared__ float sm[256], ss[256];
    sm[t] = m; ss[t] = s;
    __syncthreads();
    for (int off = 128; off > 0; off >>= 1) {
        if (t < off) {
            float m2 = sm[t + off], s2 = ss[t + off];
            float M = fmaxf(sm[t], m2);
            ss[t] = ss[t] * __expf(sm[t] - M) + s2 * __expf(m2 - M);
            sm[t] = M;
        }
        __syncthreads();
    }
    if (t == 0) { pm[b * 8 + c] = sm[0]; ps[b * 8 + c] = ss[0]; }
}

// ---------------- column softmax stats, stage 2 ----------------
__global__ void __launch_bounds__(64) cs2_k(const float* __restrict__ pm,
                                            const float* __restrict__ ps,
                                            float* __restrict__ colm,
                                            float* __restrict__ cols) {
    int b = threadIdx.x;
    if (b >= 32) return;
    float m = -3.4e38f, s = 0.f;
    for (int c = 0; c < 8; c++) {
        float m2 = pm[b * 8 + c], s2 = ps[b * 8 + c];
        float M = fmaxf(m, m2);
        s = s * __expf(m - M) + s2 * __expf(m2 - M);
        m = M;
    }
    colm[b] = m;
    cols[b] = logf(s);
}

__global__ void __launch_bounds__(256) final_k(const float* __restrict__ S,
                                               const float* __restrict__ colm,
                                               const float* __restrict__ cols,
                                               float* __restrict__ out) {
    int idx = blockIdx.x * 256 + threadIdx.x;
    if (idx >= N_NODES * 32) return;
    int b = idx & 31;
    out[idx] = S[idx] - colm[b] - cols[b];
}

extern "C" void kernel_launch(void* const* d_in, const int* in_sizes, int n_in,
                              void* d_out, int out_size, void* d_ws, size_t ws_size,
                              hipStream_t stream) {
    const float* x       = (const float*)d_in[0];
    const int*   ei      = (const int*)d_in[1];
    const float* lh      = (const float*)d_in[2];
    const float* W1_rel  = (const float*)d_in[3];
    const float* W1_root = (const float*)d_in[4];
    const float* b1      = (const float*)d_in[5];
    const float* W2_rel  = (const float*)d_in[6];
    const float* W2_root = (const float*)d_in[7];
    const float* b2      = (const float*)d_in[8];
    const float* Wp      = (const float*)d_in[9];
    const float* bp      = (const float*)d_in[10];
    float* out = (float*)d_out;
    float* ws  = (float*)d_ws;

    // workspace layout (float elements)
    unsigned short* tbf = (unsigned short*)ws;  // 6,400,000 ushorts = 3.2M floats
    float* buf1 = ws + 3200000;             // 6,400,000  (root)
    float* buf2 = ws + 9600000;             // 6,400,000  (h)
    int*   cnt  = (int*)(ws + 16000000);    // 50,000
    int*   row  = (int*)(ws + 16050048);    // 50,001
    int*   cur  = (int*)(ws + 16100096);    // 50,000
    int*   bsum = (int*)(ws + 16150144);    // 64
    float* ME   = ws + 16150272;            // 4,096
    float* colm = ws + 16154368;            // 32
    float* cols = ws + 16154400;            // 32
    float* pm   = ws + 16154432;            // 256
    float* ps   = ws + 16154688;            // 256
    int*   ssrc = (int*)(ws + 16155008);    // 640,000
    float* S    = ws + 16795008;            // 1,600,000

    const int* srcp = ei;
    const int* dstp = ei + N_EDGES;

    dim3 g_gemm(782, 2);
    const int e_grid  = (N_EDGES + 255) / 256;
    const int n_grid  = (N_NODES + 255) / 256;
    const int ew_grid = (N_NODES * 32 + 255) / 256;
    const int agg_grid = (N_NODES + 3) / 4;

    me_k<<<16, 256, 0, stream>>>(lh, Wp, bp, ME);

    // ---- CSR build ----
    zero_cnt_k<<<n_grid, 256, 0, stream>>>(cnt, N_NODES);
    hist_k<<<e_grid, 256, 0, stream>>>(dstp, cnt);
    scan1_k<<<49, 256, 0, stream>>>(cnt, row, bsum);
    scan2_k<<<1, 64, 0, stream>>>(bsum, 49);
    scan3_k<<<n_grid, 256, 0, stream>>>(row, bsum, cur);
    place_k<<<e_grid, 256, 0, stream>>>(srcp, dstp, cur, ssrc);

    // ---- layer 1 ----
    gemm128_bf16_k<<<g_gemm, 256, 0, stream>>>(x, W1_rel, tbf, N_NODES);   // t1 (bf16)
    gemm128_k<<<g_gemm, 256, 0, stream>>>(x, W1_root, buf1, N_NODES);      // root1
    agg_k<<<agg_grid, 256, 0, stream>>>(row, ssrc, tbf, buf1, b1, buf2);   // h1

    // ---- layer 2 ----
    gemm128_bf16_k<<<g_gemm, 256, 0, stream>>>(buf2, W2_rel, tbf, N_NODES);  // t2 (bf16)
    gemm128_k<<<g_gemm, 256, 0, stream>>>(buf2, W2_root, buf1, N_NODES);     // root2
    agg_k<<<agg_grid, 256, 0, stream>>>(row, ssrc, tbf, buf1, b2, buf2);     // h2

    // ---- scores + column log-softmax ----
    scores_k<<<N_NODES / 8, 256, 0, stream>>>(buf2, ME, S);
    cs1_k<<<dim3(32, 8), 256, 0, stream>>>(S, pm, ps);
    cs2_k<<<1, 64, 0, stream>>>(pm, ps, colm, cols);
    final_k<<<ew_grid, 256, 0, stream>>>(S, colm, cols, out);
}

// Round 4
// 375.297 us; speedup vs baseline: 2.6524x; 1.2155x over previous
//
#include <hip/hip_runtime.h>
#include <hip/hip_bf16.h>

#define N_NODES 50000
#define N_EDGES 640000
// FEAT = EMB = 128, HID = 512, B = 32

typedef __attribute__((ext_vector_type(8))) short short8;   // 8 x bf16 (4 VGPRs)
typedef __attribute__((ext_vector_type(4))) float floatx4;  // MFMA C/D

__device__ __forceinline__ float bf2f(unsigned short u) {
    return __uint_as_float(((unsigned int)u) << 16);
}
__device__ __forceinline__ unsigned short f2bf(float x) {
    unsigned int u = __float_as_uint(x);
    u = (u + 0x7fffu + ((u >> 16) & 1u)) >> 16;   // RNE
    return (unsigned short)u;
}

// ---------------- fp32 -> bf16 cast (x) ----------------
__global__ void __launch_bounds__(256) cvt_bf16_k(const float4* __restrict__ in,
                                                  ushort4* __restrict__ outp, int n4) {
    int i = blockIdx.x * 256 + threadIdx.x;
    if (i < n4) {
        float4 v = in[i];
        ushort4 o;
        o.x = f2bf(v.x); o.y = f2bf(v.y); o.z = f2bf(v.z); o.w = f2bf(v.w);
        outp[i] = o;
    }
}

// ---------------- pack 4 weight mats: Wt[n][k] = bf16(W[k][n]) ----------------
__global__ void __launch_bounds__(256) pack4_k(const float* __restrict__ W0,
                                               const float* __restrict__ W1,
                                               const float* __restrict__ W2,
                                               const float* __restrict__ W3,
                                               unsigned short* __restrict__ T0,
                                               unsigned short* __restrict__ T1,
                                               unsigned short* __restrict__ T2,
                                               unsigned short* __restrict__ T3) {
    int idx = blockIdx.x * 256 + threadIdx.x;     // 0..65535
    int w = idx >> 14;
    int r = idx & 16383;
    int n = r >> 7, k = r & 127;
    const float* W = (w == 0) ? W0 : (w == 1) ? W1 : (w == 2) ? W2 : W3;
    unsigned short* T = (w == 0) ? T0 : (w == 1) ? T1 : (w == 2) ? T2 : T3;
    T[r] = f2bf(W[k * 128 + n]);
}

// ---------------- CSR build ----------------
__global__ void __launch_bounds__(256) zero_cnt_k(int* __restrict__ p, int n) {
    int i = blockIdx.x * 256 + threadIdx.x;
    if (i < n) p[i] = 0;
}
__global__ void __launch_bounds__(256) hist_k(const int* __restrict__ dst,
                                              int* __restrict__ cnt) {
    int e = blockIdx.x * 256 + threadIdx.x;
    if (e < N_EDGES) atomicAdd(&cnt[dst[e]], 1);
}
__global__ void __launch_bounds__(256) scan1_k(const int* __restrict__ cnt,
                                               int* __restrict__ row,
                                               int* __restrict__ bsum) {
    __shared__ int sm[256];
    int t = threadIdx.x;
    int base = blockIdx.x * 1024 + t * 4;
    int c0 = (base + 0 < N_NODES) ? cnt[base + 0] : 0;
    int c1 = (base + 1 < N_NODES) ? cnt[base + 1] : 0;
    int c2 = (base + 2 < N_NODES) ? cnt[base + 2] : 0;
    int c3 = (base + 3 < N_NODES) ? cnt[base + 3] : 0;
    int s4 = c0 + c1 + c2 + c3;
    sm[t] = s4;
    __syncthreads();
    for (int off = 1; off < 256; off <<= 1) {
        int v = (t >= off) ? sm[t - off] : 0;
        __syncthreads();
        sm[t] += v;
        __syncthreads();
    }
    int excl = sm[t] - s4;
    if (base + 0 < N_NODES) row[base + 0] = excl;
    if (base + 1 < N_NODES) row[base + 1] = excl + c0;
    if (base + 2 < N_NODES) row[base + 2] = excl + c0 + c1;
    if (base + 3 < N_NODES) row[base + 3] = excl + c0 + c1 + c2;
    if (t == 255) bsum[blockIdx.x] = sm[255];
}
__global__ void __launch_bounds__(64) scan2_k(int* __restrict__ bsum, int nb) {
    if (threadIdx.x == 0 && blockIdx.x == 0) {
        int running = 0;
        for (int k = 0; k < nb; k++) { int v = bsum[k]; bsum[k] = running; running += v; }
    }
}
__global__ void __launch_bounds__(256) scan3_k(int* __restrict__ row,
                                               const int* __restrict__ bsum,
                                               int* __restrict__ cur) {
    int i = blockIdx.x * 256 + threadIdx.x;
    if (i < N_NODES) {
        int v = row[i] + bsum[i >> 10];
        row[i] = v;
        cur[i] = v;
        if (i == 0) row[N_NODES] = N_EDGES;
    }
}
__global__ void __launch_bounds__(256) place_k(const int* __restrict__ src,
                                               const int* __restrict__ dst,
                                               int* __restrict__ cur,
                                               int* __restrict__ ssrc) {
    int e = blockIdx.x * 256 + threadIdx.x;
    if (e < N_EDGES) {
        int p = atomicAdd(&cur[dst[e]], 1);
        ssrc[p] = src[e];
    }
}

// ---------------- fused dual MFMA GEMM: Trel=bf16(A@Wrel), Croot=A@Wroot ----------------
// A bf16 [M,128]; Bt mats are bf16 transposed [n][k]; wave = 16 rows x 128 cols.
__global__ void __launch_bounds__(256) gemm_dual_k(const unsigned short* __restrict__ A,
                                                   const unsigned short* __restrict__ BtRel,
                                                   const unsigned short* __restrict__ BtRoot,
                                                   unsigned short* __restrict__ Trel,
                                                   float* __restrict__ Croot, int M) {
    int wid = threadIdx.x >> 6, lane = threadIdx.x & 63;
    int r0 = blockIdx.x * 64 + wid * 16;
    int m = lane & 15, g = lane >> 4;            // A row / k-group
    int row = r0 + m;
    int rowc = (row < M) ? row : (M - 1);
    short8 a[4];
    #pragma unroll
    for (int kt = 0; kt < 4; kt++)
        a[kt] = *(const short8*)(A + (size_t)rowc * 128 + kt * 32 + g * 8);
    floatx4 accR[8], accO[8];
    #pragma unroll
    for (int ct = 0; ct < 8; ct++) {
        accR[ct] = (floatx4)(0.f);
        accO[ct] = (floatx4)(0.f);
    }
    #pragma unroll
    for (int ct = 0; ct < 8; ct++) {
        const unsigned short* br = BtRel  + (size_t)(ct * 16 + m) * 128 + g * 8;
        const unsigned short* bo = BtRoot + (size_t)(ct * 16 + m) * 128 + g * 8;
        #pragma unroll
        for (int kt = 0; kt < 4; kt++) {
            short8 bR = *(const short8*)(br + kt * 32);
            accR[ct] = __builtin_amdgcn_mfma_f32_16x16x32_bf16(a[kt], bR, accR[ct], 0, 0, 0);
            short8 bO = *(const short8*)(bo + kt * 32);
            accO[ct] = __builtin_amdgcn_mfma_f32_16x16x32_bf16(a[kt], bO, accO[ct], 0, 0, 0);
        }
    }
    // C/D layout: col = lane&15, row = (lane>>4)*4 + reg
    #pragma unroll
    for (int ct = 0; ct < 8; ct++) {
        #pragma unroll
        for (int rg = 0; rg < 4; rg++) {
            int ro = r0 + g * 4 + rg;
            if (ro < M) {
                int co = ct * 16 + m;
                Trel[(size_t)ro * 128 + co]  = f2bf(accR[ct][rg]);
                Croot[(size_t)ro * 128 + co] = accO[ct][rg];
            }
        }
    }
}

// ---------------- scores MFMA GEMM: S[N,32] = hb @ MEb^T ----------------
__global__ void __launch_bounds__(256) gemm_scores_k(const unsigned short* __restrict__ A,
                                                     const unsigned short* __restrict__ Bt,
                                                     float* __restrict__ S, int M) {
    int wid = threadIdx.x >> 6, lane = threadIdx.x & 63;
    int r0 = blockIdx.x * 64 + wid * 16;
    int m = lane & 15, g = lane >> 4;
    int row = r0 + m;
    int rowc = (row < M) ? row : (M - 1);
    short8 a[4];
    #pragma unroll
    for (int kt = 0; kt < 4; kt++)
        a[kt] = *(const short8*)(A + (size_t)rowc * 128 + kt * 32 + g * 8);
    floatx4 acc[2];
    acc[0] = (floatx4)(0.f);
    acc[1] = (floatx4)(0.f);
    #pragma unroll
    for (int ct = 0; ct < 2; ct++) {
        const unsigned short* b = Bt + (size_t)(ct * 16 + m) * 128 + g * 8;
        #pragma unroll
        for (int kt = 0; kt < 4; kt++) {
            short8 bv = *(const short8*)(b + kt * 32);
            acc[ct] = __builtin_amdgcn_mfma_f32_16x16x32_bf16(a[kt], bv, acc[ct], 0, 0, 0);
        }
    }
    #pragma unroll
    for (int ct = 0; ct < 2; ct++) {
        #pragma unroll
        for (int rg = 0; rg < 4; rg++) {
            int ro = r0 + g * 4 + rg;
            if (ro < M) S[(size_t)ro * 32 + ct * 16 + m] = acc[ct][rg];
        }
    }
}

// ---------------- fused gather-aggregate + mean + root + bias + relu -> bf16 h ----------------
__global__ void __launch_bounds__(256) agg_k(const int* __restrict__ row,
                                             const int* __restrict__ ssrc,
                                             const unsigned short* __restrict__ t,
                                             const float* __restrict__ root,
                                             const float* __restrict__ bias,
                                             unsigned short* __restrict__ hout) {
    int node = blockIdx.x * 4 + (threadIdx.x >> 6);
    if (node >= N_NODES) return;
    int lane = threadIdx.x & 63;
    int beg = row[node], end = row[node + 1];
    float a0 = 0.f, a1 = 0.f;
    int e = beg;
    for (; e + 1 < end; e += 2) {
        int s0 = ssrc[e], s1 = ssrc[e + 1];
        ushort2 u0 = *(const ushort2*)(t + (size_t)s0 * 128 + lane * 2);
        ushort2 u1 = *(const ushort2*)(t + (size_t)s1 * 128 + lane * 2);
        a0 += bf2f(u0.x) + bf2f(u1.x);
        a1 += bf2f(u0.y) + bf2f(u1.y);
    }
    if (e < end) {
        int s0 = ssrc[e];
        ushort2 u0 = *(const ushort2*)(t + (size_t)s0 * 128 + lane * 2);
        a0 += bf2f(u0.x);
        a1 += bf2f(u0.y);
    }
    float inv = 1.f / fmaxf((float)(end - beg), 1.f);
    int f = lane * 2;
    float2 r = *(const float2*)(root + (size_t)node * 128 + f);
    float v0 = fmaxf(a0 * inv + r.x + bias[f + 0], 0.f);
    float v1 = fmaxf(a1 * inv + r.y + bias[f + 1], 0.f);
    ushort2 o;
    o.x = f2bf(v0);
    o.y = f2bf(v1);
    *(ushort2*)(hout + (size_t)node * 128 + f) = o;
}

// ---------------- message_embed (fp32 compute, bf16 packed out) ----------------
__global__ void __launch_bounds__(256) me_k(const float* __restrict__ lh,
                                            const float* __restrict__ Wp,
                                            const float* __restrict__ bp,
                                            unsigned short* __restrict__ meb) {
    int o = blockIdx.x * 256 + threadIdx.x;
    if (o >= 32 * 128) return;
    int i = o >> 7, c = o & 127;
    float acc = bp[c];
    for (int k = 0; k < 512; k++)
        acc += lh[i * 512 + k] * Wp[k * 128 + c];
    meb[o] = f2bf(acc);   // MEb[b][k] row-major == Bt layout for scores
}

// ---------------- column softmax stats ----------------
__global__ void __launch_bounds__(256) cs1_k(const float* __restrict__ S,
                                             float* __restrict__ pm,
                                             float* __restrict__ ps) {
    int b = blockIdx.x;
    int c = blockIdx.y;
    int t = threadIdx.x;
    int lo = c * 6250;
    int hi = min(lo + 6250, N_NODES);
    float m = -3.4e38f, s = 0.f;
    for (int i = lo + t; i < hi; i += 256) {
        float v = S[(size_t)i * 32 + b];
        if (v > m) { s = s * __expf(m - v) + 1.f; m = v; }
        else       { s += __expf(v - m); }
    }
    __shared__ float sm[256], ss[256];
    sm[t] = m; ss[t] = s;
    __syncthreads();
    for (int off = 128; off > 0; off >>= 1) {
        if (t < off) {
            float m2 = sm[t + off], s2 = ss[t + off];
            float M = fmaxf(sm[t], m2);
            ss[t] = ss[t] * __expf(sm[t] - M) + s2 * __expf(m2 - M);
            sm[t] = M;
        }
        __syncthreads();
    }
    if (t == 0) { pm[b * 8 + c] = sm[0]; ps[b * 8 + c] = ss[0]; }
}
__global__ void __launch_bounds__(64) cs2_k(const float* __restrict__ pm,
                                            const float* __restrict__ ps,
                                            float* __restrict__ colm,
                                            float* __restrict__ cols) {
    int b = threadIdx.x;
    if (b >= 32) return;
    float m = -3.4e38f, s = 0.f;
    for (int c = 0; c < 8; c++) {
        float m2 = pm[b * 8 + c], s2 = ps[b * 8 + c];
        float M = fmaxf(m, m2);
        s = s * __expf(m - M) + s2 * __expf(m2 - M);
        m = M;
    }
    colm[b] = m;
    cols[b] = logf(s);
}
__global__ void __launch_bounds__(256) final_k(const float* __restrict__ S,
                                               const float* __restrict__ colm,
                                               const float* __restrict__ cols,
                                               float* __restrict__ out) {
    int idx = blockIdx.x * 256 + threadIdx.x;
    if (idx >= N_NODES * 32) return;
    int b = idx & 31;
    out[idx] = S[idx] - colm[b] - cols[b];
}

extern "C" void kernel_launch(void* const* d_in, const int* in_sizes, int n_in,
                              void* d_out, int out_size, void* d_ws, size_t ws_size,
                              hipStream_t stream) {
    const float* x       = (const float*)d_in[0];
    const int*   ei      = (const int*)d_in[1];
    const float* lh      = (const float*)d_in[2];
    const float* W1_rel  = (const float*)d_in[3];
    const float* W1_root = (const float*)d_in[4];
    const float* b1      = (const float*)d_in[5];
    const float* W2_rel  = (const float*)d_in[6];
    const float* W2_root = (const float*)d_in[7];
    const float* b2      = (const float*)d_in[8];
    const float* Wp      = (const float*)d_in[9];
    const float* bp      = (const float*)d_in[10];
    float* out = (float*)d_out;
    float* ws  = (float*)d_ws;

    // workspace layout (float-element offsets)
    unsigned short* xb   = (unsigned short*)(ws);              // 6.4M bf16 = 3.2M fl
    unsigned short* tbf  = (unsigned short*)(ws + 3200000);    // rel table bf16
    float*          rootf = ws + 6400000;                      // 6.4M fl
    unsigned short* hb   = (unsigned short*)(ws + 12800000);   // h bf16
    unsigned short* Wt1r = (unsigned short*)(ws + 16000000);   // 16384 us = 8192 fl
    unsigned short* Wt1o = (unsigned short*)(ws + 16008192);
    unsigned short* Wt2r = (unsigned short*)(ws + 16016384);
    unsigned short* Wt2o = (unsigned short*)(ws + 16024576);
    unsigned short* MEb  = (unsigned short*)(ws + 16032768);   // 4096 us
    float* pm   = ws + 16036864;                               // 256
    float* ps   = ws + 16037120;                               // 256
    float* colm = ws + 16037376;                               // 32
    float* cols = ws + 16037408;                               // 32
    int*   cnt  = (int*)(ws + 16037440);                       // 50,000
    int*   row  = (int*)(ws + 16087440);                       // 50,001
    int*   cur  = (int*)(ws + 16137444);                       // 50,000
    int*   bsum = (int*)(ws + 16187444);                       // 64
    int*   ssrc = (int*)(ws + 16187508);                       // 640,000
    float* S    = ws + 16827508;                               // 1,600,000

    const int* srcp = ei;
    const int* dstp = ei + N_EDGES;

    const int e_grid   = (N_EDGES + 255) / 256;
    const int n_grid   = (N_NODES + 255) / 256;
    const int ew_grid  = (N_NODES * 32 + 255) / 256;
    const int agg_grid = (N_NODES + 3) / 4;
    const int mm_grid  = (N_NODES + 63) / 64;   // 782

    // prep (independent)
    me_k<<<16, 256, 0, stream>>>(lh, Wp, bp, MEb);
    pack4_k<<<256, 256, 0, stream>>>(W1_rel, W1_root, W2_rel, W2_root, Wt1r, Wt1o, Wt2r, Wt2o);
    cvt_bf16_k<<<6250, 256, 0, stream>>>((const float4*)x, (ushort4*)xb, 1600000);

    // CSR build
    zero_cnt_k<<<n_grid, 256, 0, stream>>>(cnt, N_NODES);
    hist_k<<<e_grid, 256, 0, stream>>>(dstp, cnt);
    scan1_k<<<49, 256, 0, stream>>>(cnt, row, bsum);
    scan2_k<<<1, 64, 0, stream>>>(bsum, 49);
    scan3_k<<<n_grid, 256, 0, stream>>>(row, bsum, cur);
    place_k<<<e_grid, 256, 0, stream>>>(srcp, dstp, cur, ssrc);

    // layer 1
    gemm_dual_k<<<mm_grid, 256, 0, stream>>>(xb, Wt1r, Wt1o, tbf, rootf, N_NODES);
    agg_k<<<agg_grid, 256, 0, stream>>>(row, ssrc, tbf, rootf, b1, hb);

    // layer 2
    gemm_dual_k<<<mm_grid, 256, 0, stream>>>(hb, Wt2r, Wt2o, tbf, rootf, N_NODES);
    agg_k<<<agg_grid, 256, 0, stream>>>(row, ssrc, tbf, rootf, b2, hb);

    // scores + column log-softmax
    gemm_scores_k<<<mm_grid, 256, 0, stream>>>(hb, MEb, S, N_NODES);
    cs1_k<<<dim3(32, 8), 256, 0, stream>>>(S, pm, ps);
    cs2_k<<<1, 64, 0, stream>>>(pm, ps, colm, cols);
    final_k<<<ew_grid, 256, 0, stream>>>(S, colm, cols, out);
}